// Round 2
// baseline (3993.939 us; speedup 1.0000x reference)
//
#include <hip/hip_runtime.h>
#include <hip/hip_bf16.h>

#define N_NODES 20000
#define N_EDGES 100000
#define ET (N_EDGES + N_NODES)   // 120000 incl. self-loops
#define G_GRAPHS 16
#define SLOPE 0.2f

__device__ __forceinline__ float lrelu(float x) { return x > 0.f ? x : SLOPE * x; }

// bf16 raw-bits <-> float
__device__ __forceinline__ float b2f(unsigned short u) {
    union { unsigned int i; float f; } v; v.i = ((unsigned int)u) << 16; return v.f;
}
__device__ __forceinline__ unsigned short f2b(float f) {
    union { float f; unsigned int i; } v; v.f = f;
    unsigned int i = v.i;
    return (unsigned short)((i + 0x7fffu + ((i >> 16) & 1u)) >> 16);  // RNE
}

__device__ int dev_lower_bound(const int* a, int n, int key) {
    int lo = 0, hi = n;
    while (lo < hi) { int mid = (lo + hi) >> 1; if (a[mid] < key) lo = mid + 1; else hi = mid; }
    return lo;
}

__global__ void zero_kernel(int* __restrict__ p, int n) {
    int i = blockIdx.x * blockDim.x + threadIdx.x;
    if (i < n) p[i] = 0;
}

// ---------------- CSR build (by dst) ----------------
__global__ void count_kernel(const int* __restrict__ ei, int* __restrict__ counts) {
    int e = blockIdx.x * blockDim.x + threadIdx.x;
    if (e >= ET) return;
    int dst = (e < N_EDGES) ? ei[N_EDGES + e] : (e - N_EDGES);
    atomicAdd(&counts[dst], 1);
}

__global__ void scan_kernel(const int* __restrict__ counts, int* __restrict__ row_ptr) {
    __shared__ int sums[256];
    int t = threadIdx.x;
    const int CH = (N_NODES + 255) / 256;  // 79
    int base = t * CH;
    int s = 0;
    for (int i = 0; i < CH; i++) { int idx = base + i; if (idx < N_NODES) s += counts[idx]; }
    sums[t] = s;
    __syncthreads();
    for (int off = 1; off < 256; off <<= 1) {
        int v = (t >= off) ? sums[t - off] : 0;
        __syncthreads();
        sums[t] += v;
        __syncthreads();
    }
    int run = (t == 0) ? 0 : sums[t - 1];
    for (int i = 0; i < CH; i++) {
        int idx = base + i;
        if (idx < N_NODES) { row_ptr[idx] = run; run += counts[idx]; }
    }
    if (t == 255) row_ptr[N_NODES] = run;
}

__global__ void fill_kernel(const int* __restrict__ ei, const int* __restrict__ row_ptr,
                            int* __restrict__ fill_cnt, int* __restrict__ col) {
    int e = blockIdx.x * blockDim.x + threadIdx.x;
    if (e >= ET) return;
    int src, dst;
    if (e < N_EDGES) { src = ei[e]; dst = ei[N_EDGES + e]; }
    else             { src = dst = e - N_EDGES; }
    int pos = atomicAdd(&fill_cnt[dst], 1);
    col[row_ptr[dst] + pos] = src;
}

// ---------------- GEMM0: x[N,32]@W0[32,128] + b0, leaky -> bf16 ----------------
__global__ void gemm0_kernel(const float* __restrict__ x, const float* __restrict__ W0,
                             const float* __restrict__ b0, unsigned short* __restrict__ h0) {
    __shared__ float xr[32];
    int n = blockIdx.x, t = threadIdx.x;  // 128 threads
    if (t < 32) xr[t] = x[n * 32 + t];
    __syncthreads();
    float acc = 0.f;
#pragma unroll
    for (int k = 0; k < 32; k++) acc += xr[k] * W0[k * 128 + t];
    h0[(size_t)n * 128 + t] = f2b(lrelu(acc + b0[t]));
}

// ---------------- Tiled GEMM: C[M,N](bf16) = A[M,K](bf16) @ B[K,N](fp32) ----------------
// BM=BN=64, BK=16, 256 threads, 4x4 micro-tile. K%16==0, N%64==0 required.
__global__ __launch_bounds__(256) void gemm_tile(const unsigned short* __restrict__ A,
                                                 const float* __restrict__ B,
                                                 unsigned short* __restrict__ C,
                                                 int M, int N, int K) {
    __shared__ float As[16][68];   // [k][m], padded
    __shared__ float Bs[16][64];   // [k][n]
    int t = threadIdx.x;
    int row0 = blockIdx.y * 64, col0 = blockIdx.x * 64;
    int tm = t >> 4, tn = t & 15;
    int ar = t >> 2, ak = (t & 3) * 4;
    int bk = t >> 4, bn4 = (t & 15) * 4;
    float acc[4][4] = {};
    for (int k0 = 0; k0 < K; k0 += 16) {
        ushort4 a4 = make_ushort4(0, 0, 0, 0);
        int arow = row0 + ar;
        if (arow < M) a4 = *(const ushort4*)&A[(size_t)arow * K + k0 + ak];
        float4 b4 = *(const float4*)&B[(size_t)(k0 + bk) * N + col0 + bn4];
        __syncthreads();
        As[ak + 0][ar] = b2f(a4.x); As[ak + 1][ar] = b2f(a4.y);
        As[ak + 2][ar] = b2f(a4.z); As[ak + 3][ar] = b2f(a4.w);
        *(float4*)&Bs[bk][bn4] = b4;
        __syncthreads();
#pragma unroll
        for (int k = 0; k < 16; k++) {
            float4 av = *(const float4*)&As[k][tm * 4];
            float4 bv = *(const float4*)&Bs[k][tn * 4];
            acc[0][0] += av.x * bv.x; acc[0][1] += av.x * bv.y; acc[0][2] += av.x * bv.z; acc[0][3] += av.x * bv.w;
            acc[1][0] += av.y * bv.x; acc[1][1] += av.y * bv.y; acc[1][2] += av.y * bv.z; acc[1][3] += av.y * bv.w;
            acc[2][0] += av.z * bv.x; acc[2][1] += av.z * bv.y; acc[2][2] += av.z * bv.z; acc[2][3] += av.z * bv.w;
            acc[3][0] += av.w * bv.x; acc[3][1] += av.w * bv.y; acc[3][2] += av.w * bv.z; acc[3][3] += av.w * bv.w;
        }
    }
#pragma unroll
    for (int i = 0; i < 4; i++) {
        int r = row0 + tm * 4 + i;
        if (r < M) {
            ushort4 o = make_ushort4(f2b(acc[i][0]), f2b(acc[i][1]), f2b(acc[i][2]), f2b(acc[i][3]));
            *(ushort4*)&C[(size_t)r * N + col0 + tn * 4] = o;
        }
    }
}

// ---------------- attention logits: es/ed[n,h] = <h[n,h,:], a_s/d[h,:]> ----------------
__global__ void att8_kernel(const unsigned short* __restrict__ h, const float* __restrict__ a_s,
                            const float* __restrict__ a_d, float* __restrict__ es,
                            float* __restrict__ ed) {
    int n = blockIdx.x, t = threadIdx.x;  // 256 threads = 8 heads x 32 lanes
    int hd = t >> 5, l = t & 31;
    const unsigned short* hr = h + (size_t)n * 2048 + hd * 256;
    const float* as_ = a_s + hd * 256;
    const float* ad_ = a_d + hd * 256;
    float s1 = 0.f, s2 = 0.f;
    for (int c = l; c < 256; c += 32) { float v = b2f(hr[c]); s1 += v * as_[c]; s2 += v * ad_[c]; }
    for (int m = 16; m >= 1; m >>= 1) { s1 += __shfl_xor(s1, m); s2 += __shfl_xor(s2, m); }
    if (l == 0) { es[n * 8 + hd] = s1; ed[n * 8 + hd] = s2; }
}

__global__ void att1_kernel(const unsigned short* __restrict__ h, const float* __restrict__ a_s,
                            const float* __restrict__ a_d, float* __restrict__ es,
                            float* __restrict__ ed) {
    int n = blockIdx.x, l = threadIdx.x;  // 64 threads
    const unsigned short* hr = h + (size_t)n * 512;
    float s1 = 0.f, s2 = 0.f;
    for (int c = l; c < 512; c += 64) { float v = b2f(hr[c]); s1 += v * a_s[c]; s2 += v * a_d[c]; }
    for (int m = 32; m >= 1; m >>= 1) { s1 += __shfl_xor(s1, m); s2 += __shfl_xor(s2, m); }
    if (l == 0) { es[n] = s1; ed[n] = s2; }
}

// ---------------- GAT aggregation: per-dst softmax + weighted gather-sum ----------------
template <int H, int C>
__global__ __launch_bounds__(256) void agg_kernel(const unsigned short* __restrict__ hmid,
                                                  const float* __restrict__ es,
                                                  const float* __restrict__ ed,
                                                  const int* __restrict__ row_ptr,
                                                  const int* __restrict__ col,
                                                  const float* __restrict__ bias,
                                                  unsigned short* __restrict__ out) {
    constexpr int HC = H * C;
    constexpr int R = HC / 256;
    __shared__ float sm_m[H], sm_den[H];
    __shared__ float sm_alpha[32][H];
    __shared__ int scol[32];
    int v = blockIdx.x, t = threadIdx.x;
    int rs = row_ptr[v], deg = row_ptr[v + 1] - rs;
    if (t < H) {
        float edv = ed[v * H + t];
        float m = -1e30f;
        for (int e = 0; e < deg; e++) {
            int s = col[rs + e];
            m = fmaxf(m, lrelu(es[s * H + t] + edv));
        }
        float den = 0.f;
        for (int e = 0; e < deg; e++) {
            int s = col[rs + e];
            den += __expf(lrelu(es[s * H + t] + edv) - m);
        }
        sm_m[t] = m;
        sm_den[t] = den;
    }
    float acc[R] = {};
    for (int cs = 0; cs < deg; cs += 32) {
        int cn = min(32, deg - cs);
        __syncthreads();                                    // prev chunk consumed; sm_m ready
        if (t < cn) scol[t] = col[rs + cs + t];
        __syncthreads();
        if (t < cn * H) {
            int ce = t / H, hh = t % H;
            int s = scol[ce];
            float val = lrelu(es[s * H + hh] + ed[v * H + hh]);
            sm_alpha[ce][hh] = __expf(val - sm_m[hh]) / (sm_den[hh] + 1e-16f);
        }
        __syncthreads();
        for (int ce = 0; ce < cn; ce++) {
            const unsigned short* hr = hmid + (size_t)scol[ce] * HC;
#pragma unroll
            for (int r = 0; r < R; r++) {
                acc[r] += sm_alpha[ce][(r * 256 + t) / C] * b2f(hr[r * 256 + t]);
            }
        }
    }
#pragma unroll
    for (int r = 0; r < R; r++) {
        int j = r * 256 + t;
        out[(size_t)v * HC + j] = f2b(lrelu(acc[r] + bias[j]));
    }
}

// ---------------- mean pool over sorted batch ----------------
__global__ void pool_kernel(const unsigned short* __restrict__ h3, const int* __restrict__ batch,
                            float* __restrict__ mean) {
    int g = blockIdx.x, t = threadIdx.x;  // 256 threads
    __shared__ int sb[2];
    if (t == 0) { sb[0] = dev_lower_bound(batch, N_NODES, g); sb[1] = dev_lower_bound(batch, N_NODES, g + 1); }
    __syncthreads();
    int start = sb[0], end = sb[1];
    float inv = 1.f / fmaxf((float)(end - start), 1.f);
    for (int c = t; c < 512; c += 256) {
        float s = 0.f;
        for (int n = start; n < end; n++) s += b2f(h3[(size_t)n * 512 + c]);
        mean[g * 512 + c] = s * inv;
    }
}

// ---------------- final: mean[16,512]@Wf[512,512]+bf, leaky ----------------
__global__ void final_kernel(const float* __restrict__ mean, const float* __restrict__ Wf,
                             const float* __restrict__ bf, float* __restrict__ out) {
    int g = blockIdx.x, t = threadIdx.x;  // 256 threads
    __shared__ float mr[512];
    for (int c = t; c < 512; c += 256) mr[c] = mean[g * 512 + c];
    __syncthreads();
    for (int j = t; j < 512; j += 256) {
        float s = 0.f;
        for (int k = 0; k < 512; k++) s += mr[k] * Wf[k * 512 + j];
        out[g * 512 + j] = lrelu(s + bf[j]);
    }
}

extern "C" void kernel_launch(void* const* d_in, const int* in_sizes, int n_in,
                              void* d_out, int out_size, void* d_ws, size_t ws_size,
                              hipStream_t stream) {
    const float* x   = (const float*)d_in[0];
    const int*   ei  = (const int*)d_in[1];
    const int*   bat = (const int*)d_in[2];
    const float* W0  = (const float*)d_in[3];
    const float* b0  = (const float*)d_in[4];
    const float* W1  = (const float*)d_in[5];
    const float* a1s = (const float*)d_in[6];
    const float* a1d = (const float*)d_in[7];
    const float* b1  = (const float*)d_in[8];
    const float* W2  = (const float*)d_in[9];
    const float* a2s = (const float*)d_in[10];
    const float* a2d = (const float*)d_in[11];
    const float* b2  = (const float*)d_in[12];
    const float* W3  = (const float*)d_in[13];
    const float* a3s = (const float*)d_in[14];
    const float* a3d = (const float*)d_in[15];
    const float* b3  = (const float*)d_in[16];
    const float* Wf  = (const float*)d_in[17];
    const float* bf  = (const float*)d_in[18];
    float* out = (float*)d_out;

    // workspace layout (~171 MB total)
    char* p = (char*)d_ws;
    unsigned short* bufA = (unsigned short*)p; p += (size_t)N_NODES * 2048 * 2;  // 81.92 MB
    unsigned short* bufB = (unsigned short*)p; p += (size_t)N_NODES * 2048 * 2;  // 81.92 MB
    unsigned short* h0   = (unsigned short*)p; p += (size_t)N_NODES * 128 * 2;   // 5.12 MB
    float* es   = (float*)p; p += (size_t)N_NODES * 8 * 4;
    float* ed   = (float*)p; p += (size_t)N_NODES * 8 * 4;
    float* mean = (float*)p; p += 16 * 512 * 4;
    int* counts  = (int*)p; p += (size_t)N_NODES * 4;
    int* row_ptr = (int*)p; p += (size_t)(N_NODES + 1) * 4;
    int* col     = (int*)p; p += (size_t)ET * 4;

    // --- CSR by dst (shared across all 3 GAT layers) ---
    zero_kernel<<<(N_NODES + 255) / 256, 256, 0, stream>>>(counts, N_NODES);
    count_kernel<<<(ET + 255) / 256, 256, 0, stream>>>(ei, counts);
    scan_kernel<<<1, 256, 0, stream>>>(counts, row_ptr);
    zero_kernel<<<(N_NODES + 255) / 256, 256, 0, stream>>>(counts, N_NODES);
    fill_kernel<<<(ET + 255) / 256, 256, 0, stream>>>(ei, row_ptr, counts, col);

    // --- embed ---
    gemm0_kernel<<<N_NODES, 128, 0, stream>>>(x, W0, b0, h0);

    dim3 g1(2048 / 64, (N_NODES + 63) / 64);
    dim3 g3(512 / 64, (N_NODES + 63) / 64);

    // --- layer 1 ---
    gemm_tile<<<g1, 256, 0, stream>>>(h0, W1, bufB, N_NODES, 2048, 128);
    att8_kernel<<<N_NODES, 256, 0, stream>>>(bufB, a1s, a1d, es, ed);
    agg_kernel<8, 256><<<N_NODES, 256, 0, stream>>>(bufB, es, ed, row_ptr, col, b1, bufA);

    // --- layer 2 ---
    gemm_tile<<<g1, 256, 0, stream>>>(bufA, W2, bufB, N_NODES, 2048, 2048);
    att8_kernel<<<N_NODES, 256, 0, stream>>>(bufB, a2s, a2d, es, ed);
    agg_kernel<8, 256><<<N_NODES, 256, 0, stream>>>(bufB, es, ed, row_ptr, col, b2, bufA);

    // --- layer 3 ---
    gemm_tile<<<g3, 256, 0, stream>>>(bufA, W3, bufB, N_NODES, 512, 2048);
    att1_kernel<<<N_NODES, 64, 0, stream>>>(bufB, a3s, a3d, es, ed);
    agg_kernel<1, 512><<<N_NODES, 256, 0, stream>>>(bufB, es, ed, row_ptr, col, b3, bufA);

    // --- pool + final ---
    pool_kernel<<<G_GRAPHS, 256, 0, stream>>>(bufA, bat, mean);
    final_kernel<<<G_GRAPHS, 256, 0, stream>>>(mean, Wf, bf, out);
}

// Round 3
// 884.639 us; speedup vs baseline: 4.5148x; 4.5148x over previous
//
#include <hip/hip_runtime.h>
#include <hip/hip_bf16.h>

#define N_NODES 20000
#define N_EDGES 100000
#define ET (N_EDGES + N_NODES)   // 120000 incl. self-loops
#define G_GRAPHS 16
#define SLOPE 0.2f

using short8  = __attribute__((ext_vector_type(8))) short;
using floatx4 = __attribute__((ext_vector_type(4))) float;

__device__ __forceinline__ float lrelu(float x) { return x > 0.f ? x : SLOPE * x; }

__device__ __forceinline__ float b2f(unsigned short u) {
    union { unsigned int i; float f; } v; v.i = ((unsigned int)u) << 16; return v.f;
}
__device__ __forceinline__ unsigned short f2b(float f) {
    union { float f; unsigned int i; } v; v.f = f;
    unsigned int i = v.i;
    return (unsigned short)((i + 0x7fffu + ((i >> 16) & 1u)) >> 16);  // RNE
}

__device__ __forceinline__ void atomicMaxF(float* addr, float val) {
    if (val >= 0.f) atomicMax((int*)addr, __float_as_int(val));
    else            atomicMin((unsigned int*)addr, (unsigned int)__float_as_int(val));
}

__device__ __forceinline__ void gld16(const void* g, void* l) {
    __builtin_amdgcn_global_load_lds((const __attribute__((address_space(1))) void*)g,
                                     (__attribute__((address_space(3))) void*)l, 16, 0, 0);
}

__device__ int dev_lower_bound(const int* a, int n, int key) {
    int lo = 0, hi = n;
    while (lo < hi) { int mid = (lo + hi) >> 1; if (a[mid] < key) lo = mid + 1; else hi = mid; }
    return lo;
}

__global__ void zero_kernel(int* __restrict__ p, int n) {
    int i = blockIdx.x * blockDim.x + threadIdx.x;
    if (i < n) p[i] = 0;
}
__global__ void fillf_kernel(float* __restrict__ p, int n, float v) {
    int i = blockIdx.x * blockDim.x + threadIdx.x;
    if (i < n) p[i] = v;
}

// ---------------- CSR build (by dst) ----------------
__global__ void count_kernel(const int* __restrict__ ei, int* __restrict__ counts) {
    int e = blockIdx.x * blockDim.x + threadIdx.x;
    if (e >= ET) return;
    int dst = (e < N_EDGES) ? ei[N_EDGES + e] : (e - N_EDGES);
    atomicAdd(&counts[dst], 1);
}

__global__ void scan_kernel(const int* __restrict__ counts, int* __restrict__ row_ptr) {
    __shared__ int sums[256];
    int t = threadIdx.x;
    const int CH = (N_NODES + 255) / 256;
    int base = t * CH;
    int s = 0;
    for (int i = 0; i < CH; i++) { int idx = base + i; if (idx < N_NODES) s += counts[idx]; }
    sums[t] = s;
    __syncthreads();
    for (int off = 1; off < 256; off <<= 1) {
        int v = (t >= off) ? sums[t - off] : 0;
        __syncthreads();
        sums[t] += v;
        __syncthreads();
    }
    int run = (t == 0) ? 0 : sums[t - 1];
    for (int i = 0; i < CH; i++) {
        int idx = base + i;
        if (idx < N_NODES) { row_ptr[idx] = run; run += counts[idx]; }
    }
    if (t == 255) row_ptr[N_NODES] = run;
}

__global__ void fill_kernel(const int* __restrict__ ei, const int* __restrict__ row_ptr,
                            int* __restrict__ fill_cnt, int* __restrict__ col) {
    int e = blockIdx.x * blockDim.x + threadIdx.x;
    if (e >= ET) return;
    int src, dst;
    if (e < N_EDGES) { src = ei[e]; dst = ei[N_EDGES + e]; }
    else             { src = dst = e - N_EDGES; }
    int pos = atomicAdd(&fill_cnt[dst], 1);
    col[row_ptr[dst] + pos] = src;
}

// ---------------- weight transpose+convert: W[K][N] fp32 -> Wt[N][K] bf16 ----------------
__global__ void transpose_kernel(const float* __restrict__ W, unsigned short* __restrict__ Wt,
                                 int K, int N) {
    __shared__ float tile[32][33];
    int bn = blockIdx.x * 32, bk = blockIdx.y * 32;
    int tx = threadIdx.x & 31, ty = threadIdx.x >> 5;  // 256 thr: ty 0..7
#pragma unroll
    for (int p = 0; p < 32; p += 8)
        tile[ty + p][tx] = W[(size_t)(bk + ty + p) * N + bn + tx];
    __syncthreads();
#pragma unroll
    for (int p = 0; p < 32; p += 8)
        Wt[(size_t)(bn + ty + p) * K + bk + tx] = f2b(tile[tx][ty + p]);
}

// ---------------- GEMM0: x[N,32]@W0[32,128] + b0, leaky -> bf16 ----------------
__global__ void gemm0_kernel(const float* __restrict__ x, const float* __restrict__ W0,
                             const float* __restrict__ b0, unsigned short* __restrict__ h0) {
    __shared__ float xr[32];
    int n = blockIdx.x, t = threadIdx.x;  // 128 threads
    if (t < 32) xr[t] = x[n * 32 + t];
    __syncthreads();
    float acc = 0.f;
#pragma unroll
    for (int k = 0; k < 32; k++) acc += xr[k] * W0[k * 128 + t];
    h0[(size_t)n * 128 + t] = f2b(lrelu(acc + b0[t]));
}

// ---------------- MFMA GEMM: C[M,N] bf16 = A[M,K] bf16 @ Bt[N,K] bf16 ----------------
// 128x128 tile, BK=32, 256 threads = 4 waves, each wave a 64x64 quadrant (4x4 frags).
// N % 128 == 0, K % 32 == 0 required; M ragged (row-clamped staging, guarded store).
__global__ __launch_bounds__(256) void gemm_mfma(const unsigned short* __restrict__ A,
                                                 const unsigned short* __restrict__ Bt,
                                                 unsigned short* __restrict__ C,
                                                 int M, int N, int K) {
    __shared__ __align__(16) unsigned short As[128][32];
    __shared__ __align__(16) unsigned short Bs[128][32];
    int t = threadIdx.x;
    int w = t >> 6, l = t & 63;
    int r0 = blockIdx.y * 128, c0 = blockIdx.x * 128;
    int wr = (w >> 1) * 64, wc = (w & 1) * 64;
    int lrow = l >> 2, lcol = (l & 3) * 8;      // staging: 4 lanes per 32-elem row
    int m16 = l & 15, q8 = (l >> 4) * 8;        // frag read coords
    floatx4 acc[4][4] = {};

    for (int k0 = 0; k0 < K; k0 += 32) {
        __syncthreads();
#pragma unroll
        for (int q = 0; q < 2; q++) {
            int row = w * 32 + q * 16 + lrow;
            int ga = min(r0 + row, M - 1);
            gld16(A + (size_t)ga * K + k0 + lcol, &As[w * 32 + q * 16][0]);
            gld16(Bt + (size_t)(c0 + row) * K + k0 + lcol, &Bs[w * 32 + q * 16][0]);
        }
        __syncthreads();
        short8 af[4], bfr[4];
#pragma unroll
        for (int i = 0; i < 4; i++) af[i] = *(const short8*)&As[wr + i * 16 + m16][q8];
#pragma unroll
        for (int j = 0; j < 4; j++) bfr[j] = *(const short8*)&Bs[wc + j * 16 + m16][q8];
#pragma unroll
        for (int i = 0; i < 4; i++)
#pragma unroll
            for (int j = 0; j < 4; j++)
                acc[i][j] = __builtin_amdgcn_mfma_f32_16x16x32_bf16(af[i], bfr[j], acc[i][j], 0, 0, 0);
    }
    int quad = l >> 4;
#pragma unroll
    for (int i = 0; i < 4; i++)
#pragma unroll
        for (int j = 0; j < 4; j++)
#pragma unroll
            for (int reg = 0; reg < 4; reg++) {
                int r = r0 + wr + i * 16 + quad * 4 + reg;
                int c = c0 + wc + j * 16 + m16;
                if (r < M) C[(size_t)r * N + c] = f2b(acc[i][j][reg]);
            }
}

// ---------------- attention logits ----------------
__global__ void att8_kernel(const unsigned short* __restrict__ h, const float* __restrict__ a_s,
                            const float* __restrict__ a_d, float* __restrict__ es,
                            float* __restrict__ ed) {
    int n = blockIdx.x, t = threadIdx.x;  // 256 = 8 heads x 32 lanes
    int hd = t >> 5, l = t & 31;
    const unsigned short* hr = h + (size_t)n * 2048 + hd * 256 + l * 8;
    const float* as_ = a_s + hd * 256 + l * 8;
    const float* ad_ = a_d + hd * 256 + l * 8;
    uint4 u = *(const uint4*)hr;
    float v[8] = { b2f((unsigned short)(u.x & 0xffff)), b2f((unsigned short)(u.x >> 16)),
                   b2f((unsigned short)(u.y & 0xffff)), b2f((unsigned short)(u.y >> 16)),
                   b2f((unsigned short)(u.z & 0xffff)), b2f((unsigned short)(u.z >> 16)),
                   b2f((unsigned short)(u.w & 0xffff)), b2f((unsigned short)(u.w >> 16)) };
    float s1 = 0.f, s2 = 0.f;
#pragma unroll
    for (int j = 0; j < 8; j++) { s1 += v[j] * as_[j]; s2 += v[j] * ad_[j]; }
    for (int m = 16; m >= 1; m >>= 1) { s1 += __shfl_xor(s1, m); s2 += __shfl_xor(s2, m); }
    if (l == 0) { es[n * 8 + hd] = s1; ed[n * 8 + hd] = s2; }
}

__global__ void att1_kernel(const unsigned short* __restrict__ h, const float* __restrict__ a_s,
                            const float* __restrict__ a_d, float* __restrict__ es,
                            float* __restrict__ ed) {
    int n = blockIdx.x, l = threadIdx.x;  // 64 threads
    const unsigned short* hr = h + (size_t)n * 512 + l * 8;
    const float* as_ = a_s + l * 8;
    const float* ad_ = a_d + l * 8;
    uint4 u = *(const uint4*)hr;
    float v[8] = { b2f((unsigned short)(u.x & 0xffff)), b2f((unsigned short)(u.x >> 16)),
                   b2f((unsigned short)(u.y & 0xffff)), b2f((unsigned short)(u.y >> 16)),
                   b2f((unsigned short)(u.z & 0xffff)), b2f((unsigned short)(u.z >> 16)),
                   b2f((unsigned short)(u.w & 0xffff)), b2f((unsigned short)(u.w >> 16)) };
    float s1 = 0.f, s2 = 0.f;
#pragma unroll
    for (int j = 0; j < 8; j++) { s1 += v[j] * as_[j]; s2 += v[j] * ad_[j]; }
    for (int m = 32; m >= 1; m >>= 1) { s1 += __shfl_xor(s1, m); s2 += __shfl_xor(s2, m); }
    if (l == 0) { es[n] = s1; ed[n] = s2; }
}

// ---------------- edge-parallel softmax stats ----------------
template <int H>
__global__ void edge_max_kernel(const int* __restrict__ ei, const float* __restrict__ es,
                                const float* __restrict__ ed, float* __restrict__ mx) {
    int idx = blockIdx.x * blockDim.x + threadIdx.x;
    if (idx >= ET * H) return;
    int e = idx / H, h = idx % H;
    int src, dst;
    if (e < N_EDGES) { src = ei[e]; dst = ei[N_EDGES + e]; }
    else             { src = dst = e - N_EDGES; }
    float lg = lrelu(es[src * H + h] + ed[dst * H + h]);
    atomicMaxF(&mx[dst * H + h], lg);
}

template <int H>
__global__ void edge_sum_kernel(const int* __restrict__ ei, const float* __restrict__ es,
                                const float* __restrict__ ed, const float* __restrict__ mx,
                                float* __restrict__ den) {
    int idx = blockIdx.x * blockDim.x + threadIdx.x;
    if (idx >= ET * H) return;
    int e = idx / H, h = idx % H;
    int src, dst;
    if (e < N_EDGES) { src = ei[e]; dst = ei[N_EDGES + e]; }
    else             { src = dst = e - N_EDGES; }
    float lg = lrelu(es[src * H + h] + ed[dst * H + h]);
    atomicAdd(&den[dst * H + h], __expf(lg - mx[dst * H + h]));
}

// ---------------- GAT aggregation: alpha-weighted gather-sum ----------------
template <int H, int C>
__global__ __launch_bounds__(256) void agg_kernel(const unsigned short* __restrict__ hmid,
                                                  const float* __restrict__ es,
                                                  const float* __restrict__ ed,
                                                  const float* __restrict__ mx,
                                                  const float* __restrict__ den,
                                                  const int* __restrict__ row_ptr,
                                                  const int* __restrict__ col,
                                                  const float* __restrict__ bias,
                                                  unsigned short* __restrict__ out) {
    constexpr int HC = H * C;
    constexpr int PT = HC / 256;            // 8 (H=8,C=256) or 2 (H=1,C=512)
    __shared__ float sm_alpha[32][H];
    __shared__ float sm_m[H], sm_den[H], sm_ed[H];
    __shared__ int scol[32];
    int v = blockIdx.x, t = threadIdx.x;
    int rs = row_ptr[v], deg = row_ptr[v + 1] - rs;
    if (t < H) { sm_m[t] = mx[v * H + t]; sm_den[t] = den[v * H + t]; sm_ed[t] = ed[v * H + t]; }
    int j0 = t * PT;
    int hd = j0 / C;
    float acc[PT] = {};
    for (int cs = 0; cs < deg; cs += 32) {
        int cn = min(32, deg - cs);
        __syncthreads();
        if (t < cn) scol[t] = col[rs + cs + t];
        __syncthreads();
        if (t < cn * H) {
            int ce = t / H, hh = t % H;
            float lg = lrelu(es[scol[ce] * H + hh] + sm_ed[hh]);
            sm_alpha[ce][hh] = __expf(lg - sm_m[hh]) / (sm_den[hh] + 1e-16f);
        }
        __syncthreads();
        for (int ce = 0; ce < cn; ce++) {
            float a = sm_alpha[ce][hd];
            const unsigned short* hr = hmid + (size_t)scol[ce] * HC + j0;
            if constexpr (PT == 8) {
                uint4 u = *(const uint4*)hr;
                acc[0] += a * b2f((unsigned short)(u.x & 0xffff));
                acc[1] += a * b2f((unsigned short)(u.x >> 16));
                acc[2] += a * b2f((unsigned short)(u.y & 0xffff));
                acc[3] += a * b2f((unsigned short)(u.y >> 16));
                acc[4] += a * b2f((unsigned short)(u.z & 0xffff));
                acc[5] += a * b2f((unsigned short)(u.z >> 16));
                acc[6] += a * b2f((unsigned short)(u.w & 0xffff));
                acc[7] += a * b2f((unsigned short)(u.w >> 16));
            } else {
                unsigned int u = *(const unsigned int*)hr;
                acc[0] += a * b2f((unsigned short)(u & 0xffff));
                acc[1] += a * b2f((unsigned short)(u >> 16));
            }
        }
    }
    unsigned short o[PT];
#pragma unroll
    for (int i = 0; i < PT; i++) o[i] = f2b(lrelu(acc[i] + bias[j0 + i]));
    if constexpr (PT == 8) {
        *(uint4*)&out[(size_t)v * HC + j0] = *(const uint4*)o;
    } else {
        *(unsigned int*)&out[(size_t)v * HC + j0] = *(const unsigned int*)o;
    }
}

// ---------------- mean pool (chunked partial sums + atomics) ----------------
__global__ void pool_kernel(const unsigned short* __restrict__ h3, const int* __restrict__ batch,
                            float* __restrict__ msum) {
    int b0 = blockIdx.x * 128, t = threadIdx.x;  // 256 thr, 2 cols each
    int nend = min(b0 + 128, N_NODES);
    int curg = batch[b0];
    float s0 = 0.f, s1 = 0.f;
    for (int n = b0; n < nend; n++) {
        int g = batch[n];
        if (g != curg) {
            atomicAdd(&msum[curg * 512 + t * 2], s0);
            atomicAdd(&msum[curg * 512 + t * 2 + 1], s1);
            s0 = s1 = 0.f; curg = g;
        }
        unsigned int u = *(const unsigned int*)&h3[(size_t)n * 512 + t * 2];
        s0 += b2f((unsigned short)(u & 0xffff));
        s1 += b2f((unsigned short)(u >> 16));
    }
    atomicAdd(&msum[curg * 512 + t * 2], s0);
    atomicAdd(&msum[curg * 512 + t * 2 + 1], s1);
}

// ---------------- final: mean[16,512]@Wf[512,512]+bf, leaky ----------------
__global__ void final_kernel(const float* __restrict__ msum, const int* __restrict__ batch,
                             const float* __restrict__ Wf, const float* __restrict__ bf,
                             float* __restrict__ out) {
    int g = blockIdx.x, t = threadIdx.x;  // 256 threads
    __shared__ float mr[512];
    __shared__ float sinv;
    if (t == 0) {
        int st = dev_lower_bound(batch, N_NODES, g);
        int en = dev_lower_bound(batch, N_NODES, g + 1);
        sinv = 1.f / fmaxf((float)(en - st), 1.f);
    }
    __syncthreads();
    for (int c = t; c < 512; c += 256) mr[c] = msum[g * 512 + c] * sinv;
    __syncthreads();
    for (int j = t; j < 512; j += 256) {
        float s = 0.f;
        for (int k = 0; k < 512; k++) s += mr[k] * Wf[k * 512 + j];
        out[g * 512 + j] = lrelu(s + bf[j]);
    }
}

extern "C" void kernel_launch(void* const* d_in, const int* in_sizes, int n_in,
                              void* d_out, int out_size, void* d_ws, size_t ws_size,
                              hipStream_t stream) {
    const float* x   = (const float*)d_in[0];
    const int*   ei  = (const int*)d_in[1];
    const int*   bat = (const int*)d_in[2];
    const float* W0  = (const float*)d_in[3];
    const float* b0  = (const float*)d_in[4];
    const float* W1  = (const float*)d_in[5];
    const float* a1s = (const float*)d_in[6];
    const float* a1d = (const float*)d_in[7];
    const float* b1  = (const float*)d_in[8];
    const float* W2  = (const float*)d_in[9];
    const float* a2s = (const float*)d_in[10];
    const float* a2d = (const float*)d_in[11];
    const float* b2  = (const float*)d_in[12];
    const float* W3  = (const float*)d_in[13];
    const float* a3s = (const float*)d_in[14];
    const float* a3d = (const float*)d_in[15];
    const float* b3  = (const float*)d_in[16];
    const float* Wf  = (const float*)d_in[17];
    const float* bf  = (const float*)d_in[18];
    float* out = (float*)d_out;

    // workspace layout (~184 MB)
    char* p = (char*)d_ws;
    unsigned short* bufA = (unsigned short*)p; p += (size_t)N_NODES * 2048 * 2;
    unsigned short* bufB = (unsigned short*)p; p += (size_t)N_NODES * 2048 * 2;
    unsigned short* h0   = (unsigned short*)p; p += (size_t)N_NODES * 128 * 2;
    unsigned short* W1t  = (unsigned short*)p; p += (size_t)2048 * 128 * 2;
    unsigned short* W2t  = (unsigned short*)p; p += (size_t)2048 * 2048 * 2;
    unsigned short* W3t  = (unsigned short*)p; p += (size_t)512 * 2048 * 2;
    float* es   = (float*)p; p += (size_t)N_NODES * 8 * 4;
    float* ed   = (float*)p; p += (size_t)N_NODES * 8 * 4;
    float* mx   = (float*)p; p += (size_t)N_NODES * 8 * 4;
    float* den  = (float*)p; p += (size_t)N_NODES * 8 * 4;
    float* msum = (float*)p; p += 16 * 512 * 4;
    int* counts  = (int*)p; p += (size_t)N_NODES * 4;
    int* row_ptr = (int*)p; p += (size_t)(N_NODES + 1) * 4;
    int* col     = (int*)p; p += (size_t)ET * 4;

    // --- CSR by dst ---
    zero_kernel<<<(N_NODES + 255) / 256, 256, 0, stream>>>(counts, N_NODES);
    count_kernel<<<(ET + 255) / 256, 256, 0, stream>>>(ei, counts);
    scan_kernel<<<1, 256, 0, stream>>>(counts, row_ptr);
    zero_kernel<<<(N_NODES + 255) / 256, 256, 0, stream>>>(counts, N_NODES);
    fill_kernel<<<(ET + 255) / 256, 256, 0, stream>>>(ei, row_ptr, counts, col);

    // --- weight transpose/convert (bf16, B^T layout) ---
    transpose_kernel<<<dim3(2048 / 32, 128 / 32), 256, 0, stream>>>(W1, W1t, 128, 2048);
    transpose_kernel<<<dim3(2048 / 32, 2048 / 32), 256, 0, stream>>>(W2, W2t, 2048, 2048);
    transpose_kernel<<<dim3(512 / 32, 2048 / 32), 256, 0, stream>>>(W3, W3t, 2048, 512);

    // --- embed ---
    gemm0_kernel<<<N_NODES, 128, 0, stream>>>(x, W0, b0, h0);

    dim3 g12(2048 / 128, (N_NODES + 127) / 128);   // (16, 157)
    dim3 g3(512 / 128, (N_NODES + 127) / 128);     // (4, 157)
    int eb8 = (ET * 8 + 255) / 256, eb1 = (ET + 255) / 256;

    // --- layer 1 ---
    gemm_mfma<<<g12, 256, 0, stream>>>(h0, W1t, bufB, N_NODES, 2048, 128);
    att8_kernel<<<N_NODES, 256, 0, stream>>>(bufB, a1s, a1d, es, ed);
    fillf_kernel<<<(N_NODES * 8 + 255) / 256, 256, 0, stream>>>(mx, N_NODES * 8, -1e30f);
    fillf_kernel<<<(N_NODES * 8 + 255) / 256, 256, 0, stream>>>(den, N_NODES * 8, 0.f);
    edge_max_kernel<8><<<eb8, 256, 0, stream>>>(ei, es, ed, mx);
    edge_sum_kernel<8><<<eb8, 256, 0, stream>>>(ei, es, ed, mx, den);
    agg_kernel<8, 256><<<N_NODES, 256, 0, stream>>>(bufB, es, ed, mx, den, row_ptr, col, b1, bufA);

    // --- layer 2 ---
    gemm_mfma<<<g12, 256, 0, stream>>>(bufA, W2t, bufB, N_NODES, 2048, 2048);
    att8_kernel<<<N_NODES, 256, 0, stream>>>(bufB, a2s, a2d, es, ed);
    fillf_kernel<<<(N_NODES * 8 + 255) / 256, 256, 0, stream>>>(mx, N_NODES * 8, -1e30f);
    fillf_kernel<<<(N_NODES * 8 + 255) / 256, 256, 0, stream>>>(den, N_NODES * 8, 0.f);
    edge_max_kernel<8><<<eb8, 256, 0, stream>>>(ei, es, ed, mx);
    edge_sum_kernel<8><<<eb8, 256, 0, stream>>>(ei, es, ed, mx, den);
    agg_kernel<8, 256><<<N_NODES, 256, 0, stream>>>(bufB, es, ed, mx, den, row_ptr, col, b2, bufA);

    // --- layer 3 ---
    gemm_mfma<<<g3, 256, 0, stream>>>(bufA, W3t, bufB, N_NODES, 512, 2048);
    att1_kernel<<<N_NODES, 64, 0, stream>>>(bufB, a3s, a3d, es, ed);
    fillf_kernel<<<(N_NODES + 255) / 256, 256, 0, stream>>>(mx, N_NODES, -1e30f);
    fillf_kernel<<<(N_NODES + 255) / 256, 256, 0, stream>>>(den, N_NODES, 0.f);
    edge_max_kernel<1><<<eb1, 256, 0, stream>>>(ei, es, ed, mx);
    edge_sum_kernel<1><<<eb1, 256, 0, stream>>>(ei, es, ed, mx, den);
    agg_kernel<1, 512><<<N_NODES, 256, 0, stream>>>(bufB, es, ed, mx, den, row_ptr, col, b3, bufA);

    // --- pool + final ---
    zero_kernel<<<(16 * 512 + 255) / 256, 256, 0, stream>>>((int*)msum, 16 * 512);
    pool_kernel<<<(N_NODES + 127) / 128, 256, 0, stream>>>(bufA, bat, msum);
    final_kernel<<<G_GRAPHS, 256, 0, stream>>>(msum, bat, Wf, bf, out);
}

// Round 4
// 836.449 us; speedup vs baseline: 4.7749x; 1.0576x over previous
//
#include <hip/hip_runtime.h>
#include <hip/hip_bf16.h>

#define N_NODES 20000
#define N_EDGES 100000
#define ET (N_EDGES + N_NODES)   // 120000 incl. self-loops
#define G_GRAPHS 16
#define SLOPE 0.2f

using short8  = __attribute__((ext_vector_type(8))) short;
using floatx4 = __attribute__((ext_vector_type(4))) float;

__device__ __forceinline__ float lrelu(float x) { return x > 0.f ? x : SLOPE * x; }

__device__ __forceinline__ float b2f(unsigned short u) {
    union { unsigned int i; float f; } v; v.i = ((unsigned int)u) << 16; return v.f;
}
__device__ __forceinline__ unsigned short f2b(float f) {
    union { float f; unsigned int i; } v; v.f = f;
    unsigned int i = v.i;
    return (unsigned short)((i + 0x7fffu + ((i >> 16) & 1u)) >> 16);  // RNE
}

__device__ __forceinline__ void gld16(const void* g, void* l) {
    __builtin_amdgcn_global_load_lds((const __attribute__((address_space(1))) void*)g,
                                     (__attribute__((address_space(3))) void*)l, 16, 0, 0);
}

__device__ int dev_lower_bound(const int* a, int n, int key) {
    int lo = 0, hi = n;
    while (lo < hi) { int mid = (lo + hi) >> 1; if (a[mid] < key) lo = mid + 1; else hi = mid; }
    return lo;
}

__global__ void zero_kernel(int* __restrict__ p, int n) {
    int i = blockIdx.x * blockDim.x + threadIdx.x;
    if (i < n) p[i] = 0;
}

// ---------------- CSR build (by dst) ----------------
__global__ void count_kernel(const int* __restrict__ ei, int* __restrict__ counts) {
    int e = blockIdx.x * blockDim.x + threadIdx.x;
    if (e >= ET) return;
    int dst = (e < N_EDGES) ? ei[N_EDGES + e] : (e - N_EDGES);
    atomicAdd(&counts[dst], 1);
}

__global__ void scan_kernel(const int* __restrict__ counts, int* __restrict__ row_ptr) {
    __shared__ int sums[256];
    int t = threadIdx.x;
    const int CH = (N_NODES + 255) / 256;
    int base = t * CH;
    int s = 0;
    for (int i = 0; i < CH; i++) { int idx = base + i; if (idx < N_NODES) s += counts[idx]; }
    sums[t] = s;
    __syncthreads();
    for (int off = 1; off < 256; off <<= 1) {
        int v = (t >= off) ? sums[t - off] : 0;
        __syncthreads();
        sums[t] += v;
        __syncthreads();
    }
    int run = (t == 0) ? 0 : sums[t - 1];
    for (int i = 0; i < CH; i++) {
        int idx = base + i;
        if (idx < N_NODES) { row_ptr[idx] = run; run += counts[idx]; }
    }
    if (t == 255) row_ptr[N_NODES] = run;
}

__global__ void fill_kernel(const int* __restrict__ ei, const int* __restrict__ row_ptr,
                            int* __restrict__ fill_cnt, int* __restrict__ col) {
    int e = blockIdx.x * blockDim.x + threadIdx.x;
    if (e >= ET) return;
    int src, dst;
    if (e < N_EDGES) { src = ei[e]; dst = ei[N_EDGES + e]; }
    else             { src = dst = e - N_EDGES; }
    int pos = atomicAdd(&fill_cnt[dst], 1);
    col[row_ptr[dst] + pos] = src;
}

// ---------------- weight transpose+convert: W[K][N] fp32 -> Wt[N][K] bf16 ----------------
__global__ void transpose_kernel(const float* __restrict__ W, unsigned short* __restrict__ Wt,
                                 int K, int N) {
    __shared__ float tile[32][33];
    int bn = blockIdx.x * 32, bk = blockIdx.y * 32;
    int tx = threadIdx.x & 31, ty = threadIdx.x >> 5;  // 256 thr: ty 0..7
#pragma unroll
    for (int p = 0; p < 32; p += 8)
        tile[ty + p][tx] = W[(size_t)(bk + ty + p) * N + bn + tx];
    __syncthreads();
#pragma unroll
    for (int p = 0; p < 32; p += 8)
        Wt[(size_t)(bn + ty + p) * K + bk + tx] = f2b(tile[tx][ty + p]);
}

// ---------------- GEMM0: x[N,32]@W0[32,128] + b0, leaky -> bf16 ----------------
__global__ void gemm0_kernel(const float* __restrict__ x, const float* __restrict__ W0,
                             const float* __restrict__ b0, unsigned short* __restrict__ h0) {
    __shared__ float xr[32];
    int n = blockIdx.x, t = threadIdx.x;  // 128 threads
    if (t < 32) xr[t] = x[n * 32 + t];
    __syncthreads();
    float acc = 0.f;
#pragma unroll
    for (int k = 0; k < 32; k++) acc += xr[k] * W0[k * 128 + t];
    h0[(size_t)n * 128 + t] = f2b(lrelu(acc + b0[t]));
}

// ---------------- MFMA GEMM: C[M,N] bf16 = A[M,K] bf16 @ Bt[N,K] bf16 ----------------
// 128x128 tile, BK=32, 256 threads = 4 waves, each wave a 64x64 quadrant (4x4 frags).
// LDS colblocks (16B = 8 bf16) XOR-swizzled by ((row>>1)&3) to kill ds_read_b128
// bank conflicts (quad reads spread over all 4 colblocks -> 2 lanes/bank-group = free).
__global__ __launch_bounds__(256) void gemm_mfma(const unsigned short* __restrict__ A,
                                                 const unsigned short* __restrict__ Bt,
                                                 unsigned short* __restrict__ C,
                                                 int M, int N, int K) {
    __shared__ __align__(16) unsigned short As[128][32];
    __shared__ __align__(16) unsigned short Bs[128][32];
    int t = threadIdx.x;
    int w = t >> 6, l = t & 63;
    int r0 = blockIdx.y * 128, c0 = blockIdx.x * 128;
    int wr = (w >> 1) * 64, wc = (w & 1) * 64;
    int lrow = l >> 2;
    int gcb  = (l & 3) ^ ((l >> 3) & 3);        // swizzled global colblock for staging
    int m16 = l & 15, qb = l >> 4;              // frag coords: row-in-16, k-block
    int sw  = (m16 >> 1) & 3;                   // read-side swizzle
    int roff = ((qb ^ sw) * 8);                 // physical element offset within row
    floatx4 acc[4][4] = {};

    for (int k0 = 0; k0 < K; k0 += 32) {
        __syncthreads();
#pragma unroll
        for (int q = 0; q < 2; q++) {
            int row = w * 32 + q * 16 + lrow;
            int ga = min(r0 + row, M - 1);
            gld16(A + (size_t)ga * K + k0 + gcb * 8, &As[w * 32 + q * 16][0]);
            gld16(Bt + (size_t)(c0 + row) * K + k0 + gcb * 8, &Bs[w * 32 + q * 16][0]);
        }
        __syncthreads();
        short8 af[4], bfr[4];
#pragma unroll
        for (int i = 0; i < 4; i++) af[i] = *(const short8*)&As[wr + i * 16 + m16][roff];
#pragma unroll
        for (int j = 0; j < 4; j++) bfr[j] = *(const short8*)&Bs[wc + j * 16 + m16][roff];
#pragma unroll
        for (int i = 0; i < 4; i++)
#pragma unroll
            for (int j = 0; j < 4; j++)
                acc[i][j] = __builtin_amdgcn_mfma_f32_16x16x32_bf16(af[i], bfr[j], acc[i][j], 0, 0, 0);
    }
    int quad = l >> 4;
#pragma unroll
    for (int i = 0; i < 4; i++)
#pragma unroll
        for (int j = 0; j < 4; j++)
#pragma unroll
            for (int reg = 0; reg < 4; reg++) {
                int r = r0 + wr + i * 16 + quad * 4 + reg;
                int c = c0 + wc + j * 16 + m16;
                if (r < M) C[(size_t)r * N + c] = f2b(acc[i][j][reg]);
            }
}

// ---------------- attention logits ----------------
__global__ void att8_kernel(const unsigned short* __restrict__ h, const float* __restrict__ a_s,
                            const float* __restrict__ a_d, float* __restrict__ es,
                            float* __restrict__ ed) {
    int n = blockIdx.x, t = threadIdx.x;  // 256 = 8 heads x 32 lanes
    int hd = t >> 5, l = t & 31;
    const unsigned short* hr = h + (size_t)n * 2048 + hd * 256 + l * 8;
    const float* as_ = a_s + hd * 256 + l * 8;
    const float* ad_ = a_d + hd * 256 + l * 8;
    uint4 u = *(const uint4*)hr;
    float v[8] = { b2f((unsigned short)(u.x & 0xffff)), b2f((unsigned short)(u.x >> 16)),
                   b2f((unsigned short)(u.y & 0xffff)), b2f((unsigned short)(u.y >> 16)),
                   b2f((unsigned short)(u.z & 0xffff)), b2f((unsigned short)(u.z >> 16)),
                   b2f((unsigned short)(u.w & 0xffff)), b2f((unsigned short)(u.w >> 16)) };
    float s1 = 0.f, s2 = 0.f;
#pragma unroll
    for (int j = 0; j < 8; j++) { s1 += v[j] * as_[j]; s2 += v[j] * ad_[j]; }
    for (int m = 16; m >= 1; m >>= 1) { s1 += __shfl_xor(s1, m); s2 += __shfl_xor(s2, m); }
    if (l == 0) { es[n * 8 + hd] = s1; ed[n * 8 + hd] = s2; }
}

__global__ void att1_kernel(const unsigned short* __restrict__ h, const float* __restrict__ a_s,
                            const float* __restrict__ a_d, float* __restrict__ es,
                            float* __restrict__ ed) {
    int n = blockIdx.x, l = threadIdx.x;  // 64 threads
    const unsigned short* hr = h + (size_t)n * 512 + l * 8;
    const float* as_ = a_s + l * 8;
    const float* ad_ = a_d + l * 8;
    uint4 u = *(const uint4*)hr;
    float v[8] = { b2f((unsigned short)(u.x & 0xffff)), b2f((unsigned short)(u.x >> 16)),
                   b2f((unsigned short)(u.y & 0xffff)), b2f((unsigned short)(u.y >> 16)),
                   b2f((unsigned short)(u.z & 0xffff)), b2f((unsigned short)(u.z >> 16)),
                   b2f((unsigned short)(u.w & 0xffff)), b2f((unsigned short)(u.w >> 16)) };
    float s1 = 0.f, s2 = 0.f;
#pragma unroll
    for (int j = 0; j < 8; j++) { s1 += v[j] * as_[j]; s2 += v[j] * ad_[j]; }
    for (int m = 32; m >= 1; m >>= 1) { s1 += __shfl_xor(s1, m); s2 += __shfl_xor(s2, m); }
    if (l == 0) { es[n] = s1; ed[n] = s2; }
}

// ---------------- fused GAT aggregation: softmax stats + weighted gather, one block/dst ----
template <int H, int C>
__global__ __launch_bounds__(256) void agg_fused(const unsigned short* __restrict__ hmid,
                                                 const float* __restrict__ es,
                                                 const float* __restrict__ ed,
                                                 const int* __restrict__ row_ptr,
                                                 const int* __restrict__ col,
                                                 const float* __restrict__ bias,
                                                 unsigned short* __restrict__ out) {
    constexpr int HC = H * C;
    constexpr int PT = HC / 256;            // 8 (H=8,C=256) or 2 (H=1,C=512)
    constexpr int LH = (H == 8) ? 3 : 0;    // log2(H)
    __shared__ float sm_ed[H], sm_m[H], sm_den[H];
    __shared__ float wpart[4 * H];
    __shared__ float sm_alpha[32][H];
    __shared__ int scol[32];
    int v = blockIdx.x, t = threadIdx.x;
    int rs = row_ptr[v], deg = row_ptr[v + 1] - rs;
    if (t < H) sm_ed[t] = ed[v * H + t];
    __syncthreads();
    int h = t & (H - 1);
    int w = t >> 6, l = t & 63;
    float edv = sm_ed[h];
    // pass A: per-head max over edges (thread t handles head t&(H-1), edges strided)
    float lmax = -1e30f;
    for (int e = t >> LH; e < deg; e += 256 / H) {
        int s = col[rs + e];
        lmax = fmaxf(lmax, lrelu(es[s * H + h] + edv));
    }
#pragma unroll
    for (int m = H; m < 64; m <<= 1) lmax = fmaxf(lmax, __shfl_xor(lmax, m));
    if (l < H) wpart[w * H + l] = lmax;
    __syncthreads();
    if (t < H)
        sm_m[t] = fmaxf(fmaxf(wpart[t], wpart[H + t]), fmaxf(wpart[2 * H + t], wpart[3 * H + t]));
    __syncthreads();
    // pass B: denominator
    float mh = sm_m[h];
    float lsum = 0.f;
    for (int e = t >> LH; e < deg; e += 256 / H) {
        int s = col[rs + e];
        lsum += __expf(lrelu(es[s * H + h] + edv) - mh);
    }
#pragma unroll
    for (int m = H; m < 64; m <<= 1) lsum += __shfl_xor(lsum, m);
    if (l < H) wpart[w * H + l] = lsum;
    __syncthreads();
    if (t < H) sm_den[t] = wpart[t] + wpart[H + t] + wpart[2 * H + t] + wpart[3 * H + t];
    // gather phase
    int j0 = t * PT;
    int hd = j0 / C;
    float acc[PT] = {};
    for (int cs = 0; cs < deg; cs += 32) {
        int cn = min(32, deg - cs);
        __syncthreads();                                  // also covers sm_den ready (1st iter)
        if (t < cn) scol[t] = col[rs + cs + t];
        __syncthreads();
        if (t < cn * H) {
            int ce = t / H, hh = t % H;
            float lg = lrelu(es[scol[ce] * H + hh] + sm_ed[hh]);
            sm_alpha[ce][hh] = __expf(lg - sm_m[hh]) / (sm_den[hh] + 1e-16f);
        }
        __syncthreads();
        for (int ce = 0; ce < cn; ce++) {
            float a = sm_alpha[ce][hd];
            const unsigned short* hr = hmid + (size_t)scol[ce] * HC + j0;
            if constexpr (PT == 8) {
                uint4 u = *(const uint4*)hr;
                acc[0] += a * b2f((unsigned short)(u.x & 0xffff));
                acc[1] += a * b2f((unsigned short)(u.x >> 16));
                acc[2] += a * b2f((unsigned short)(u.y & 0xffff));
                acc[3] += a * b2f((unsigned short)(u.y >> 16));
                acc[4] += a * b2f((unsigned short)(u.z & 0xffff));
                acc[5] += a * b2f((unsigned short)(u.z >> 16));
                acc[6] += a * b2f((unsigned short)(u.w & 0xffff));
                acc[7] += a * b2f((unsigned short)(u.w >> 16));
            } else {
                unsigned int u = *(const unsigned int*)hr;
                acc[0] += a * b2f((unsigned short)(u & 0xffff));
                acc[1] += a * b2f((unsigned short)(u >> 16));
            }
        }
    }
    unsigned short o[PT];
#pragma unroll
    for (int i = 0; i < PT; i++) o[i] = f2b(lrelu(acc[i] + bias[j0 + i]));
    if constexpr (PT == 8) {
        *(uint4*)&out[(size_t)v * HC + j0] = *(const uint4*)o;
    } else {
        *(unsigned int*)&out[(size_t)v * HC + j0] = *(const unsigned int*)o;
    }
}

// ---------------- mean pool (chunked partial sums + atomics) ----------------
__global__ void pool_kernel(const unsigned short* __restrict__ h3, const int* __restrict__ batch,
                            float* __restrict__ msum) {
    int b0 = blockIdx.x * 128, t = threadIdx.x;  // 256 thr, 2 cols each
    int nend = min(b0 + 128, N_NODES);
    int curg = batch[b0];
    float s0 = 0.f, s1 = 0.f;
    for (int n = b0; n < nend; n++) {
        int g = batch[n];
        if (g != curg) {
            atomicAdd(&msum[curg * 512 + t * 2], s0);
            atomicAdd(&msum[curg * 512 + t * 2 + 1], s1);
            s0 = s1 = 0.f; curg = g;
        }
        unsigned int u = *(const unsigned int*)&h3[(size_t)n * 512 + t * 2];
        s0 += b2f((unsigned short)(u & 0xffff));
        s1 += b2f((unsigned short)(u >> 16));
    }
    atomicAdd(&msum[curg * 512 + t * 2], s0);
    atomicAdd(&msum[curg * 512 + t * 2 + 1], s1);
}

// ---------------- final: mean[16,512]@Wf[512,512]+bf, leaky ----------------
__global__ void final_kernel(const float* __restrict__ msum, const int* __restrict__ batch,
                             const float* __restrict__ Wf, const float* __restrict__ bf,
                             float* __restrict__ out) {
    int g = blockIdx.x, t = threadIdx.x;  // 256 threads
    __shared__ float mr[512];
    __shared__ float sinv;
    if (t == 0) {
        int st = dev_lower_bound(batch, N_NODES, g);
        int en = dev_lower_bound(batch, N_NODES, g + 1);
        sinv = 1.f / fmaxf((float)(en - st), 1.f);
    }
    __syncthreads();
    for (int c = t; c < 512; c += 256) mr[c] = msum[g * 512 + c] * sinv;
    __syncthreads();
    for (int j = t; j < 512; j += 256) {
        float s = 0.f;
        for (int k = 0; k < 512; k++) s += mr[k] * Wf[k * 512 + j];
        out[g * 512 + j] = lrelu(s + bf[j]);
    }
}

extern "C" void kernel_launch(void* const* d_in, const int* in_sizes, int n_in,
                              void* d_out, int out_size, void* d_ws, size_t ws_size,
                              hipStream_t stream) {
    const float* x   = (const float*)d_in[0];
    const int*   ei  = (const int*)d_in[1];
    const int*   bat = (const int*)d_in[2];
    const float* W0  = (const float*)d_in[3];
    const float* b0  = (const float*)d_in[4];
    const float* W1  = (const float*)d_in[5];
    const float* a1s = (const float*)d_in[6];
    const float* a1d = (const float*)d_in[7];
    const float* b1  = (const float*)d_in[8];
    const float* W2  = (const float*)d_in[9];
    const float* a2s = (const float*)d_in[10];
    const float* a2d = (const float*)d_in[11];
    const float* b2  = (const float*)d_in[12];
    const float* W3  = (const float*)d_in[13];
    const float* a3s = (const float*)d_in[14];
    const float* a3d = (const float*)d_in[15];
    const float* b3  = (const float*)d_in[16];
    const float* Wf  = (const float*)d_in[17];
    const float* bf  = (const float*)d_in[18];
    float* out = (float*)d_out;

    // workspace layout (~184 MB)
    char* p = (char*)d_ws;
    unsigned short* bufA = (unsigned short*)p; p += (size_t)N_NODES * 2048 * 2;
    unsigned short* bufB = (unsigned short*)p; p += (size_t)N_NODES * 2048 * 2;
    unsigned short* h0   = (unsigned short*)p; p += (size_t)N_NODES * 128 * 2;
    unsigned short* W1t  = (unsigned short*)p; p += (size_t)2048 * 128 * 2;
    unsigned short* W2t  = (unsigned short*)p; p += (size_t)2048 * 2048 * 2;
    unsigned short* W3t  = (unsigned short*)p; p += (size_t)512 * 2048 * 2;
    float* es   = (float*)p; p += (size_t)N_NODES * 8 * 4;
    float* ed   = (float*)p; p += (size_t)N_NODES * 8 * 4;
    float* msum = (float*)p; p += 16 * 512 * 4;
    int* counts  = (int*)p; p += (size_t)N_NODES * 4;
    int* row_ptr = (int*)p; p += (size_t)(N_NODES + 1) * 4;
    int* col     = (int*)p; p += (size_t)ET * 4;

    // --- CSR by dst ---
    zero_kernel<<<(N_NODES + 255) / 256, 256, 0, stream>>>(counts, N_NODES);
    count_kernel<<<(ET + 255) / 256, 256, 0, stream>>>(ei, counts);
    scan_kernel<<<1, 256, 0, stream>>>(counts, row_ptr);
    zero_kernel<<<(N_NODES + 255) / 256, 256, 0, stream>>>(counts, N_NODES);
    fill_kernel<<<(ET + 255) / 256, 256, 0, stream>>>(ei, row_ptr, counts, col);

    // --- weight transpose/convert (bf16, B^T layout) ---
    transpose_kernel<<<dim3(2048 / 32, 128 / 32), 256, 0, stream>>>(W1, W1t, 128, 2048);
    transpose_kernel<<<dim3(2048 / 32, 2048 / 32), 256, 0, stream>>>(W2, W2t, 2048, 2048);
    transpose_kernel<<<dim3(512 / 32, 2048 / 32), 256, 0, stream>>>(W3, W3t, 2048, 512);

    // --- embed ---
    gemm0_kernel<<<N_NODES, 128, 0, stream>>>(x, W0, b0, h0);

    dim3 g12(2048 / 128, (N_NODES + 127) / 128);   // (16, 157)
    dim3 g3(512 / 128, (N_NODES + 127) / 128);     // (4, 157)

    // --- layer 1 ---
    gemm_mfma<<<g12, 256, 0, stream>>>(h0, W1t, bufB, N_NODES, 2048, 128);
    att8_kernel<<<N_NODES, 256, 0, stream>>>(bufB, a1s, a1d, es, ed);
    agg_fused<8, 256><<<N_NODES, 256, 0, stream>>>(bufB, es, ed, row_ptr, col, b1, bufA);

    // --- layer 2 ---
    gemm_mfma<<<g12, 256, 0, stream>>>(bufA, W2t, bufB, N_NODES, 2048, 2048);
    att8_kernel<<<N_NODES, 256, 0, stream>>>(bufB, a2s, a2d, es, ed);
    agg_fused<8, 256><<<N_NODES, 256, 0, stream>>>(bufB, es, ed, row_ptr, col, b2, bufA);

    // --- layer 3 ---
    gemm_mfma<<<g3, 256, 0, stream>>>(bufA, W3t, bufB, N_NODES, 512, 2048);
    att1_kernel<<<N_NODES, 64, 0, stream>>>(bufB, a3s, a3d, es, ed);
    agg_fused<1, 512><<<N_NODES, 256, 0, stream>>>(bufB, es, ed, row_ptr, col, b3, bufA);

    // --- pool + final ---
    zero_kernel<<<(16 * 512 + 255) / 256, 256, 0, stream>>>((int*)msum, 16 * 512);
    pool_kernel<<<(N_NODES + 127) / 128, 256, 0, stream>>>(bufA, bat, msum);
    final_kernel<<<G_GRAPHS, 256, 0, stream>>>(msum, bat, Wf, bf, out);
}

// Round 5
// 823.675 us; speedup vs baseline: 4.8489x; 1.0155x over previous
//
#include <hip/hip_runtime.h>
#include <hip/hip_bf16.h>

#define N_NODES 20000
#define N_EDGES 100000
#define ET (N_EDGES + N_NODES)   // 120000 incl. self-loops
#define G_GRAPHS 16
#define SLOPE 0.2f

using short8  = __attribute__((ext_vector_type(8))) short;
using floatx4 = __attribute__((ext_vector_type(4))) float;

__device__ __forceinline__ float lrelu(float x) { return x > 0.f ? x : SLOPE * x; }

__device__ __forceinline__ float b2f(unsigned short u) {
    union { unsigned int i; float f; } v; v.i = ((unsigned int)u) << 16; return v.f;
}
__device__ __forceinline__ unsigned short f2b(float f) {
    union { float f; unsigned int i; } v; v.f = f;
    unsigned int i = v.i;
    return (unsigned short)((i + 0x7fffu + ((i >> 16) & 1u)) >> 16);  // RNE
}

__device__ __forceinline__ void gld16(const void* g, void* l) {
    __builtin_amdgcn_global_load_lds((const __attribute__((address_space(1))) void*)g,
                                     (__attribute__((address_space(3))) void*)l, 16, 0, 0);
}

__device__ int dev_lower_bound(const int* a, int n, int key) {
    int lo = 0, hi = n;
    while (lo < hi) { int mid = (lo + hi) >> 1; if (a[mid] < key) lo = mid + 1; else hi = mid; }
    return lo;
}

__global__ void zero_kernel(int* __restrict__ p, int n) {
    int i = blockIdx.x * blockDim.x + threadIdx.x;
    if (i < n) p[i] = 0;
}

// ---------------- CSR build (by dst) ----------------
__global__ void count_kernel(const int* __restrict__ ei, int* __restrict__ counts) {
    int e = blockIdx.x * blockDim.x + threadIdx.x;
    if (e >= ET) return;
    int dst = (e < N_EDGES) ? ei[N_EDGES + e] : (e - N_EDGES);
    atomicAdd(&counts[dst], 1);
}

__global__ void scan_kernel(const int* __restrict__ counts, int* __restrict__ row_ptr) {
    __shared__ int sums[256];
    int t = threadIdx.x;
    const int CH = (N_NODES + 255) / 256;
    int base = t * CH;
    int s = 0;
    for (int i = 0; i < CH; i++) { int idx = base + i; if (idx < N_NODES) s += counts[idx]; }
    sums[t] = s;
    __syncthreads();
    for (int off = 1; off < 256; off <<= 1) {
        int v = (t >= off) ? sums[t - off] : 0;
        __syncthreads();
        sums[t] += v;
        __syncthreads();
    }
    int run = (t == 0) ? 0 : sums[t - 1];
    for (int i = 0; i < CH; i++) {
        int idx = base + i;
        if (idx < N_NODES) { row_ptr[idx] = run; run += counts[idx]; }
    }
    if (t == 255) row_ptr[N_NODES] = run;
}

__global__ void fill_kernel(const int* __restrict__ ei, const int* __restrict__ row_ptr,
                            int* __restrict__ fill_cnt, int* __restrict__ col) {
    int e = blockIdx.x * blockDim.x + threadIdx.x;
    if (e >= ET) return;
    int src, dst;
    if (e < N_EDGES) { src = ei[e]; dst = ei[N_EDGES + e]; }
    else             { src = dst = e - N_EDGES; }
    int pos = atomicAdd(&fill_cnt[dst], 1);
    col[row_ptr[dst] + pos] = src;
}

// ---------------- weight transpose+convert: W[K][N] fp32 -> Wt[N][K] bf16 ----------------
__global__ void transpose_kernel(const float* __restrict__ W, unsigned short* __restrict__ Wt,
                                 int K, int N) {
    __shared__ float tile[32][33];
    int bn = blockIdx.x * 32, bk = blockIdx.y * 32;
    int tx = threadIdx.x & 31, ty = threadIdx.x >> 5;  // 256 thr: ty 0..7
#pragma unroll
    for (int p = 0; p < 32; p += 8)
        tile[ty + p][tx] = W[(size_t)(bk + ty + p) * N + bn + tx];
    __syncthreads();
#pragma unroll
    for (int p = 0; p < 32; p += 8)
        Wt[(size_t)(bn + ty + p) * K + bk + tx] = f2b(tile[tx][ty + p]);
}

// ---------------- GEMM0: x[N,32]@W0[32,128] + b0, leaky -> bf16 ----------------
__global__ void gemm0_kernel(const float* __restrict__ x, const float* __restrict__ W0,
                             const float* __restrict__ b0, unsigned short* __restrict__ h0) {
    __shared__ float xr[32];
    int n = blockIdx.x, t = threadIdx.x;  // 128 threads
    if (t < 32) xr[t] = x[n * 32 + t];
    __syncthreads();
    float acc = 0.f;
#pragma unroll
    for (int k = 0; k < 32; k++) acc += xr[k] * W0[k * 128 + t];
    h0[(size_t)n * 128 + t] = f2b(lrelu(acc + b0[t]));
}

// ---------------- MFMA GEMM: C[M,N] bf16 = A[M,K] bf16 @ Bt[N,K] bf16 ----------------
// 128x128 tile, BK=32, 256 threads = 4 waves, each wave a 64x64 quadrant (4x4 frags).
// LDS colblocks XOR-swizzled (conflict-free). MFMA operands SWAPPED (mfma(b,a)) so the
// acc reg dimension indexes consecutive C columns -> ushort4 (8B) stores, 16/lane not 64.
__global__ __launch_bounds__(256) void gemm_mfma(const unsigned short* __restrict__ A,
                                                 const unsigned short* __restrict__ Bt,
                                                 unsigned short* __restrict__ C,
                                                 int M, int N, int K) {
    __shared__ __align__(16) unsigned short As[128][32];
    __shared__ __align__(16) unsigned short Bs[128][32];
    int t = threadIdx.x;
    int w = t >> 6, l = t & 63;
    int r0 = blockIdx.y * 128, c0 = blockIdx.x * 128;
    int wr = (w >> 1) * 64, wc = (w & 1) * 64;
    int lrow = l >> 2;
    int gcb  = (l & 3) ^ ((l >> 3) & 3);        // swizzled global colblock for staging
    int m16 = l & 15, qb = l >> 4;              // frag coords: row-in-16, k-block
    int sw  = (m16 >> 1) & 3;                   // read-side swizzle
    int roff = ((qb ^ sw) * 8);                 // physical element offset within row
    floatx4 acc[4][4] = {};

    for (int k0 = 0; k0 < K; k0 += 32) {
        __syncthreads();
#pragma unroll
        for (int q = 0; q < 2; q++) {
            int row = w * 32 + q * 16 + lrow;
            int ga = min(r0 + row, M - 1);
            gld16(A + (size_t)ga * K + k0 + gcb * 8, &As[w * 32 + q * 16][0]);
            gld16(Bt + (size_t)(c0 + row) * K + k0 + gcb * 8, &Bs[w * 32 + q * 16][0]);
        }
        __syncthreads();
        short8 af[4], bfr[4];
#pragma unroll
        for (int i = 0; i < 4; i++) af[i] = *(const short8*)&As[wr + i * 16 + m16][roff];
#pragma unroll
        for (int j = 0; j < 4; j++) bfr[j] = *(const short8*)&Bs[wc + j * 16 + m16][roff];
#pragma unroll
        for (int i = 0; i < 4; i++)
#pragma unroll
            for (int j = 0; j < 4; j++)
                acc[i][j] = __builtin_amdgcn_mfma_f32_16x16x32_bf16(bfr[j], af[i], acc[i][j], 0, 0, 0);
    }
    // swapped operands => acc[i][j] reg dim = consecutive C columns, lane&15 = C row
    int quad = l >> 4;
#pragma unroll
    for (int i = 0; i < 4; i++) {
        int r = r0 + wr + i * 16 + m16;
        if (r < M) {
#pragma unroll
            for (int j = 0; j < 4; j++) {
                int c = c0 + wc + j * 16 + quad * 4;
                ushort4 o = make_ushort4(f2b(acc[i][j][0]), f2b(acc[i][j][1]),
                                         f2b(acc[i][j][2]), f2b(acc[i][j][3]));
                *(ushort4*)&C[(size_t)r * N + c] = o;
            }
        }
    }
}

// ---------------- attention logits ----------------
__global__ void att8_kernel(const unsigned short* __restrict__ h, const float* __restrict__ a_s,
                            const float* __restrict__ a_d, float* __restrict__ es,
                            float* __restrict__ ed) {
    int n = blockIdx.x, t = threadIdx.x;  // 256 = 8 heads x 32 lanes
    int hd = t >> 5, l = t & 31;
    const unsigned short* hr = h + (size_t)n * 2048 + hd * 256 + l * 8;
    const float* as_ = a_s + hd * 256 + l * 8;
    const float* ad_ = a_d + hd * 256 + l * 8;
    uint4 u = *(const uint4*)hr;
    float v[8] = { b2f((unsigned short)(u.x & 0xffff)), b2f((unsigned short)(u.x >> 16)),
                   b2f((unsigned short)(u.y & 0xffff)), b2f((unsigned short)(u.y >> 16)),
                   b2f((unsigned short)(u.z & 0xffff)), b2f((unsigned short)(u.z >> 16)),
                   b2f((unsigned short)(u.w & 0xffff)), b2f((unsigned short)(u.w >> 16)) };
    float s1 = 0.f, s2 = 0.f;
#pragma unroll
    for (int j = 0; j < 8; j++) { s1 += v[j] * as_[j]; s2 += v[j] * ad_[j]; }
    for (int m = 16; m >= 1; m >>= 1) { s1 += __shfl_xor(s1, m); s2 += __shfl_xor(s2, m); }
    if (l == 0) { es[n * 8 + hd] = s1; ed[n * 8 + hd] = s2; }
}

__global__ void att1_kernel(const unsigned short* __restrict__ h, const float* __restrict__ a_s,
                            const float* __restrict__ a_d, float* __restrict__ es,
                            float* __restrict__ ed) {
    int n = blockIdx.x, l = threadIdx.x;  // 64 threads
    const unsigned short* hr = h + (size_t)n * 512 + l * 8;
    const float* as_ = a_s + l * 8;
    const float* ad_ = a_d + l * 8;
    uint4 u = *(const uint4*)hr;
    float v[8] = { b2f((unsigned short)(u.x & 0xffff)), b2f((unsigned short)(u.x >> 16)),
                   b2f((unsigned short)(u.y & 0xffff)), b2f((unsigned short)(u.y >> 16)),
                   b2f((unsigned short)(u.z & 0xffff)), b2f((unsigned short)(u.z >> 16)),
                   b2f((unsigned short)(u.w & 0xffff)), b2f((unsigned short)(u.w >> 16)) };
    float s1 = 0.f, s2 = 0.f;
#pragma unroll
    for (int j = 0; j < 8; j++) { s1 += v[j] * as_[j]; s2 += v[j] * ad_[j]; }
    for (int m = 32; m >= 1; m >>= 1) { s1 += __shfl_xor(s1, m); s2 += __shfl_xor(s2, m); }
    if (l == 0) { es[n] = s1; ed[n] = s2; }
}

// ---------------- single-pass GAT aggregation ----------------
// softmax without max-subtraction (logits are O(10), exp safe in fp32; mathematically
// identical to the max-subtracted form): acc += exp(lg)*h, den += exp(lg), divide at end.
template <int H, int C>
__global__ __launch_bounds__(256) void agg_fused(const unsigned short* __restrict__ hmid,
                                                 const float* __restrict__ es,
                                                 const float* __restrict__ ed,
                                                 const int* __restrict__ row_ptr,
                                                 const int* __restrict__ col,
                                                 const float* __restrict__ bias,
                                                 unsigned short* __restrict__ out) {
    constexpr int HC = H * C;
    constexpr int PT = HC / 256;            // 8 (H=8,C=256) or 2 (H=1,C=512)
    __shared__ float sm_ed[H];
    __shared__ float sm_ex[32][H];
    __shared__ int scol[32];
    int v = blockIdx.x, t = threadIdx.x;
    int rs = row_ptr[v], deg = row_ptr[v + 1] - rs;
    if (t < H) sm_ed[t] = ed[v * H + t];
    int j0 = t * PT;
    int hd = j0 / C;
    float acc[PT] = {};
    float den = 0.f;
    for (int cs = 0; cs < deg; cs += 32) {
        int cn = min(32, deg - cs);
        __syncthreads();                    // protect scol/sm_ex from previous iteration
        if (t < cn) scol[t] = col[rs + cs + t];
        __syncthreads();
        if (t < cn * H) {
            int ce = t / H, hh = t % H;
            sm_ex[ce][hh] = __expf(lrelu(es[scol[ce] * H + hh] + sm_ed[hh]));
        }
        __syncthreads();
        for (int ce = 0; ce < cn; ce++) {
            float a = sm_ex[ce][hd];
            den += a;
            const unsigned short* hr = hmid + (size_t)scol[ce] * HC + j0;
            if constexpr (PT == 8) {
                uint4 u = *(const uint4*)hr;
                acc[0] += a * b2f((unsigned short)(u.x & 0xffff));
                acc[1] += a * b2f((unsigned short)(u.x >> 16));
                acc[2] += a * b2f((unsigned short)(u.y & 0xffff));
                acc[3] += a * b2f((unsigned short)(u.y >> 16));
                acc[4] += a * b2f((unsigned short)(u.z & 0xffff));
                acc[5] += a * b2f((unsigned short)(u.z >> 16));
                acc[6] += a * b2f((unsigned short)(u.w & 0xffff));
                acc[7] += a * b2f((unsigned short)(u.w >> 16));
            } else {
                unsigned int u = *(const unsigned int*)hr;
                acc[0] += a * b2f((unsigned short)(u & 0xffff));
                acc[1] += a * b2f((unsigned short)(u >> 16));
            }
        }
    }
    float inv = 1.f / (den + 1e-16f);
    unsigned short o[PT];
#pragma unroll
    for (int i = 0; i < PT; i++) o[i] = f2b(lrelu(acc[i] * inv + bias[j0 + i]));
    if constexpr (PT == 8) {
        *(uint4*)&out[(size_t)v * HC + j0] = *(const uint4*)o;
    } else {
        *(unsigned int*)&out[(size_t)v * HC + j0] = *(const unsigned int*)o;
    }
}

// ---------------- mean pool (chunked partial sums + atomics) ----------------
__global__ void pool_kernel(const unsigned short* __restrict__ h3, const int* __restrict__ batch,
                            float* __restrict__ msum) {
    int b0 = blockIdx.x * 128, t = threadIdx.x;  // 256 thr, 2 cols each
    int nend = min(b0 + 128, N_NODES);
    int curg = batch[b0];
    float s0 = 0.f, s1 = 0.f;
    for (int n = b0; n < nend; n++) {
        int g = batch[n];
        if (g != curg) {
            atomicAdd(&msum[curg * 512 + t * 2], s0);
            atomicAdd(&msum[curg * 512 + t * 2 + 1], s1);
            s0 = s1 = 0.f; curg = g;
        }
        unsigned int u = *(const unsigned int*)&h3[(size_t)n * 512 + t * 2];
        s0 += b2f((unsigned short)(u & 0xffff));
        s1 += b2f((unsigned short)(u >> 16));
    }
    atomicAdd(&msum[curg * 512 + t * 2], s0);
    atomicAdd(&msum[curg * 512 + t * 2 + 1], s1);
}

// ---------------- final: mean[16,512]@Wf[512,512]+bf, leaky ----------------
__global__ void final_kernel(const float* __restrict__ msum, const int* __restrict__ batch,
                             const float* __restrict__ Wf, const float* __restrict__ bf,
                             float* __restrict__ out) {
    int g = blockIdx.x, t = threadIdx.x;  // 256 threads
    __shared__ float mr[512];
    __shared__ float sinv;
    if (t == 0) {
        int st = dev_lower_bound(batch, N_NODES, g);
        int en = dev_lower_bound(batch, N_NODES, g + 1);
        sinv = 1.f / fmaxf((float)(en - st), 1.f);
    }
    __syncthreads();
    for (int c = t; c < 512; c += 256) mr[c] = msum[g * 512 + c] * sinv;
    __syncthreads();
    for (int j = t; j < 512; j += 256) {
        float s = 0.f;
        for (int k = 0; k < 512; k++) s += mr[k] * Wf[k * 512 + j];
        out[g * 512 + j] = lrelu(s + bf[j]);
    }
}

extern "C" void kernel_launch(void* const* d_in, const int* in_sizes, int n_in,
                              void* d_out, int out_size, void* d_ws, size_t ws_size,
                              hipStream_t stream) {
    const float* x   = (const float*)d_in[0];
    const int*   ei  = (const int*)d_in[1];
    const int*   bat = (const int*)d_in[2];
    const float* W0  = (const float*)d_in[3];
    const float* b0  = (const float*)d_in[4];
    const float* W1  = (const float*)d_in[5];
    const float* a1s = (const float*)d_in[6];
    const float* a1d = (const float*)d_in[7];
    const float* b1  = (const float*)d_in[8];
    const float* W2  = (const float*)d_in[9];
    const float* a2s = (const float*)d_in[10];
    const float* a2d = (const float*)d_in[11];
    const float* b2  = (const float*)d_in[12];
    const float* W3  = (const float*)d_in[13];
    const float* a3s = (const float*)d_in[14];
    const float* a3d = (const float*)d_in[15];
    const float* b3  = (const float*)d_in[16];
    const float* Wf  = (const float*)d_in[17];
    const float* bf  = (const float*)d_in[18];
    float* out = (float*)d_out;

    // workspace layout (~184 MB)
    char* p = (char*)d_ws;
    unsigned short* bufA = (unsigned short*)p; p += (size_t)N_NODES * 2048 * 2;
    unsigned short* bufB = (unsigned short*)p; p += (size_t)N_NODES * 2048 * 2;
    unsigned short* h0   = (unsigned short*)p; p += (size_t)N_NODES * 128 * 2;
    unsigned short* W1t  = (unsigned short*)p; p += (size_t)2048 * 128 * 2;
    unsigned short* W2t  = (unsigned short*)p; p += (size_t)2048 * 2048 * 2;
    unsigned short* W3t  = (unsigned short*)p; p += (size_t)512 * 2048 * 2;
    float* es   = (float*)p; p += (size_t)N_NODES * 8 * 4;
    float* ed   = (float*)p; p += (size_t)N_NODES * 8 * 4;
    float* msum = (float*)p; p += 16 * 512 * 4;
    int* counts  = (int*)p; p += (size_t)N_NODES * 4;
    int* row_ptr = (int*)p; p += (size_t)(N_NODES + 1) * 4;
    int* col     = (int*)p; p += (size_t)ET * 4;

    // --- CSR by dst ---
    zero_kernel<<<(N_NODES + 255) / 256, 256, 0, stream>>>(counts, N_NODES);
    count_kernel<<<(ET + 255) / 256, 256, 0, stream>>>(ei, counts);
    scan_kernel<<<1, 256, 0, stream>>>(counts, row_ptr);
    zero_kernel<<<(N_NODES + 255) / 256, 256, 0, stream>>>(counts, N_NODES);
    fill_kernel<<<(ET + 255) / 256, 256, 0, stream>>>(ei, row_ptr, counts, col);

    // --- weight transpose/convert (bf16, B^T layout) ---
    transpose_kernel<<<dim3(2048 / 32, 128 / 32), 256, 0, stream>>>(W1, W1t, 128, 2048);
    transpose_kernel<<<dim3(2048 / 32, 2048 / 32), 256, 0, stream>>>(W2, W2t, 2048, 2048);
    transpose_kernel<<<dim3(512 / 32, 2048 / 32), 256, 0, stream>>>(W3, W3t, 2048, 512);

    // --- embed ---
    gemm0_kernel<<<N_NODES, 128, 0, stream>>>(x, W0, b0, h0);

    dim3 g12(2048 / 128, (N_NODES + 127) / 128);   // (16, 157)
    dim3 g3(512 / 128, (N_NODES + 127) / 128);     // (4, 157)

    // --- layer 1 ---
    gemm_mfma<<<g12, 256, 0, stream>>>(h0, W1t, bufB, N_NODES, 2048, 128);
    att8_kernel<<<N_NODES, 256, 0, stream>>>(bufB, a1s, a1d, es, ed);
    agg_fused<8, 256><<<N_NODES, 256, 0, stream>>>(bufB, es, ed, row_ptr, col, b1, bufA);

    // --- layer 2 ---
    gemm_mfma<<<g12, 256, 0, stream>>>(bufA, W2t, bufB, N_NODES, 2048, 2048);
    att8_kernel<<<N_NODES, 256, 0, stream>>>(bufB, a2s, a2d, es, ed);
    agg_fused<8, 256><<<N_NODES, 256, 0, stream>>>(bufB, es, ed, row_ptr, col, b2, bufA);

    // --- layer 3 ---
    gemm_mfma<<<g3, 256, 0, stream>>>(bufA, W3t, bufB, N_NODES, 512, 2048);
    att1_kernel<<<N_NODES, 64, 0, stream>>>(bufB, a3s, a3d, es, ed);
    agg_fused<1, 512><<<N_NODES, 256, 0, stream>>>(bufB, es, ed, row_ptr, col, b3, bufA);

    // --- pool + final ---
    zero_kernel<<<(16 * 512 + 255) / 256, 256, 0, stream>>>((int*)msum, 16 * 512);
    pool_kernel<<<(N_NODES + 127) / 128, 256, 0, stream>>>(bufA, bat, msum);
    final_kernel<<<G_GRAPHS, 256, 0, stream>>>(msum, bat, Wf, bf, out);
}